// Round 4
// baseline (1376.614 us; speedup 1.0000x reference)
//
#include <hip/hip_runtime.h>
#include <hip/hip_bf16.h>
#include <math.h>

// Problem dims (fixed by reference)
#define B_SZ 256
#define P_SZ 256
#define LD   128   // L_DIM (evolving part)
#define ZD   256   // Z_DIM
#define HD   256   // H_DIM
#define NSTEP 8            // RK4 macro steps over [0,1]
#define SPAN (P_SZ/NSTEP)  // fine intervals per macro step = 32
#define TT   16            // points per block in decode kernel

__device__ __forceinline__ float fast_tanh(float v) {
  float e = __expf(2.0f * fabsf(v));
  float r = 1.0f - 2.0f / (e + 1.0f);
  return copysignf(r, v);
}

__device__ __forceinline__ unsigned int bf_bits(float f) {
  unsigned int u = __float_as_uint(f);
  return (u + 0x7fffu + ((u >> 16) & 1u)) >> 16;   // RNE
}
__device__ __forceinline__ float bf_lo(unsigned int u) {
  return __uint_as_float(u << 16);
}
__device__ __forceinline__ float bf_hi(unsigned int u) {
  return __uint_as_float(u & 0xffff0000u);
}
// opaque register pin: compiler cannot rematerialize past this
__device__ __forceinline__ void pin(uint2& w) {
  asm volatile("" : "+v"(w.x), "+v"(w.y));
}

// ---------------------------------------------------------------------------
// Prep: pack W1[0:128], W2, W3, Wh[1:129] into bf16 k-pair uint2 layout.
// ---------------------------------------------------------------------------
__global__ __launch_bounds__(256) void pack_kernel(
    const float* __restrict__ W1, const float* __restrict__ W2,
    const float* __restrict__ W3, const float* __restrict__ Wh,
    uint2* __restrict__ W1q, uint2* __restrict__ W2q,
    uint2* __restrict__ W3q, uint2* __restrict__ Whq)
{
  int idx = blockIdx.x * 256 + threadIdx.x;
  if (idx < 8192) {
    int r = idx >> 8, u = idx & 255, k = r * 4;
    uint2 o;
    o.x = bf_bits(W1[(k + 0) * HD + u]) | (bf_bits(W1[(k + 1) * HD + u]) << 16);
    o.y = bf_bits(W1[(k + 2) * HD + u]) | (bf_bits(W1[(k + 3) * HD + u]) << 16);
    W1q[idx] = o;
  } else if (idx < 24576) {
    int i = idx - 8192;
    int r = i >> 8, u = i & 255, k = r * 4;
    uint2 o;
    o.x = bf_bits(W2[(k + 0) * HD + u]) | (bf_bits(W2[(k + 1) * HD + u]) << 16);
    o.y = bf_bits(W2[(k + 2) * HD + u]) | (bf_bits(W2[(k + 3) * HD + u]) << 16);
    W2q[i] = o;
  } else if (idx < 32768) {
    int i = idx - 24576;
    int r = i >> 7, u = i & 127, k = r * 4;
    uint2 o;
    o.x = bf_bits(W3[(k + 0) * LD + u]) | (bf_bits(W3[(k + 1) * LD + u]) << 16);
    o.y = bf_bits(W3[(k + 2) * LD + u]) | (bf_bits(W3[(k + 3) * LD + u]) << 16);
    W3q[i] = o;
  } else {
    int i = idx - 32768;
    int r = i >> 8, u = i & 255, k = r * 4;
    uint2 o;
    o.x = bf_bits(Wh[(1 + k) * HD + u]) | (bf_bits(Wh[(2 + k) * HD + u]) << 16);
    o.y = bf_bits(Wh[(3 + k) * HD + u]) | (bf_bits(Wh[(4 + k) * HD + u]) << 16);
    Whq[i] = o;
  }
}

// ---------------------------------------------------------------------------
// Kernel 1: one batch row per block, 256 threads, 2 output units per thread.
// Weights PINNED register-resident (bf16 packed, 256 VGPRs/thread).
// RK4 + cubic-Hermite dense output -> latent (bf16).
// ---------------------------------------------------------------------------
__global__ __launch_bounds__(256, 1) void ode_kernel(
    const float* __restrict__ x, const float* __restrict__ z,
    const float* __restrict__ x0,
    const float* __restrict__ W1, const float* __restrict__ b1,
    const float* __restrict__ b2, const float* __restrict__ b3,
    const uint2* __restrict__ W1q, const uint2* __restrict__ W2q,
    const uint2* __restrict__ W3q,
    __hip_bfloat16* __restrict__ latent)
{
  __shared__ float times[P_SZ + 1];
  __shared__ float vL[LD], vNew[LD], vin[LD], zf[LD];
  __shared__ float kb0[LD], kb1[LD], kb2[LD], kb3[LD];
  __shared__ float c1[HD], h1s[HD], h2s[HD];
  __shared__ float part[2][HD];   // L1/L2 split-K partials
  __shared__ float pt3[4][LD];    // L3 split-K partials

  const int tid = threadIdx.x;
  const int b   = blockIdx.x;
  const int ua  = tid & 127;        // unit a (layers 1/2); unit b = ua+128
  const int ub  = ua + 128;
  const int h2i = tid >> 7;         // split-K half (layers 1/2)
  const int va  = tid & 63;         // unit a (layer 3); unit b = va+64
  const int vb  = va + 64;
  const int s4  = tid >> 6;         // split-K quarter (layer 3)

  // ---- load this thread's weight slices into registers (once), pin them ----
  uint2 rw1a[16], rw1b[16], rw2a[32], rw2b[32], rw3a[16], rw3b[16];
#pragma unroll
  for (int i = 0; i < 16; i++) {
    rw1a[i] = W1q[(h2i * 16 + i) * HD + ua];
    rw1b[i] = W1q[(h2i * 16 + i) * HD + ub];
  }
#pragma unroll
  for (int i = 0; i < 32; i++) {
    rw2a[i] = W2q[(h2i * 32 + i) * HD + ua];
    rw2b[i] = W2q[(h2i * 32 + i) * HD + ub];
  }
#pragma unroll
  for (int i = 0; i < 16; i++) {
    rw3a[i] = W3q[(s4 * 16 + i) * LD + va];
    rw3b[i] = W3q[(s4 * 16 + i) * LD + vb];
  }
#pragma unroll
  for (int i = 0; i < 16; i++) { pin(rw1a[i]); pin(rw1b[i]); pin(rw3a[i]); pin(rw3b[i]); }
#pragma unroll
  for (int i = 0; i < 32; i++) { pin(rw2a[i]); pin(rw2b[i]); }

  const float b2r  = b2[tid];              // for h2s write (unit = tid)
  const float b3r  = b3[tid & 127];        // for kout write (unit = tid, tid<128)
  const float w1ta = W1[ZD * HD + ua];     // W1 time row (fp32)
  const float w1tb = W1[ZD * HD + ub];

  for (int m = tid; m <= P_SZ; m += 256) times[m] = (m == 0) ? x0[0] : x[m - 1];
  if (tid < LD) {
    vL[tid] = z[b * ZD + tid];
    zf[tid] = z[b * ZD + LD + tid];
    kb0[tid] = 0.f;
  }
  __syncthreads();

  // c1[u] = b1[u] + zf . W1[128..255][u]  (fp32, once per block)
  {
    float aa = 0.f, ab = 0.f;
    int kb = h2i * 64;
#pragma unroll 4
    for (int k = kb; k < kb + 64; k += 4) {
      float4 zv = *(const float4*)&zf[k];
      aa += zv.x * W1[(LD + k + 0) * HD + ua] + zv.y * W1[(LD + k + 1) * HD + ua]
          + zv.z * W1[(LD + k + 2) * HD + ua] + zv.w * W1[(LD + k + 3) * HD + ua];
      ab += zv.x * W1[(LD + k + 0) * HD + ub] + zv.y * W1[(LD + k + 1) * HD + ub]
          + zv.z * W1[(LD + k + 2) * HD + ub] + zv.w * W1[(LD + k + 3) * HD + ub];
    }
    part[h2i][ua] = aa;
    __syncthreads();
    if (tid < HD) c1[tid] = b1[tid] + part[0][tid] + part[1][tid];
    __syncthreads();
    part[h2i][ua] = ab;   // reuse buffer for ub half
    __syncthreads();
    // note: part[h2i][ua] currently holds ub's partial; c1[ub] = b1+p0+p1 indexed by ua
    if (tid < LD) c1[tid + 128] = b1[tid + 128] + part[0][tid] + part[1][tid];
    __syncthreads();
  }

  // kout = f_L(t, vsrc + c*kin)
  auto eval_f = [&](float t, float* vsrc, float* kin, float c, float* kout) {
    if (tid < LD) vin[tid] = vsrc[tid] + c * kin[tid];
    __syncthreads();
    // layer 1 (K = 64 per half from registers; zf+b1 folded into c1; + time)
    {
      float a0 = 0.f, a1 = 0.f, b0 = 0.f, b1v = 0.f;
#pragma unroll
      for (int i = 0; i < 16; i++) {
        float4 vv = *(const float4*)&vin[h2i * 64 + i * 4];
        uint2 wa = rw1a[i], wb = rw1b[i];
        a0 += vv.x * bf_lo(wa.x) + vv.y * bf_hi(wa.x);
        a1 += vv.z * bf_lo(wa.y) + vv.w * bf_hi(wa.y);
        b0 += vv.x * bf_lo(wb.x) + vv.y * bf_hi(wb.x);
        b1v += vv.z * bf_lo(wb.y) + vv.w * bf_hi(wb.y);
      }
      float acca = a0 + a1, accb = b0 + b1v;
      acca += (h2i == 0) ? c1[ua] : t * w1ta;
      accb += (h2i == 0) ? c1[ub] : t * w1tb;
      part[h2i][ua] = acca;
      __syncthreads();
      if (tid < HD) { float s = part[0][tid] + part[1][tid]; h2s[tid] = s; }
      __syncthreads();
      part[h2i][ua] = accb;
      __syncthreads();
      // h2s[] temporarily holds unit-a pre-activations for units 0..255? No:
      // h2s[tid] holds pre-act of unit 'tid' only for tid<128 path... see below.
      if (tid < LD)  h1s[tid] = fast_tanh(h2s[tid]);                         // units 0..127
      if (tid >= LD) h1s[tid] = fast_tanh(part[0][tid - 128] + part[1][tid - 128]); // units 128..255
      __syncthreads();
    }
    // layer 2 (K = 128 per half from registers)
    {
      float a0 = 0.f, a1 = 0.f, b0 = 0.f, b1v = 0.f;
#pragma unroll
      for (int i = 0; i < 32; i++) {
        float4 hv = *(const float4*)&h1s[h2i * 128 + i * 4];
        uint2 wa = rw2a[i], wb = rw2b[i];
        a0 += hv.x * bf_lo(wa.x) + hv.y * bf_hi(wa.x);
        a1 += hv.z * bf_lo(wa.y) + hv.w * bf_hi(wa.y);
        b0 += hv.x * bf_lo(wb.x) + hv.y * bf_hi(wb.x);
        b1v += hv.z * bf_lo(wb.y) + hv.w * bf_hi(wb.y);
      }
      float acca = a0 + a1, accb = b0 + b1v;
      part[h2i][ua] = acca;
      __syncthreads();
      if (tid < HD) { float s = part[0][tid] + part[1][tid]; vNewDummy: ; h2s[tid] = s; }
      __syncthreads();
      part[h2i][ua] = accb;
      __syncthreads();
      if (tid < LD)  h2s[tid] = fast_tanh(h2s[tid] + b2r);
      if (tid >= LD) h2s[tid] = fast_tanh(part[0][tid - 128] + part[1][tid - 128] + b2r);
      __syncthreads();
    }
    // layer 3 (K = 64 per quarter from registers)
    {
      float a0 = 0.f, a1 = 0.f, b0 = 0.f, b1v = 0.f;
#pragma unroll
      for (int i = 0; i < 16; i++) {
        float4 hv = *(const float4*)&h2s[s4 * 64 + i * 4];
        uint2 wa = rw3a[i], wb = rw3b[i];
        a0 += hv.x * bf_lo(wa.x) + hv.y * bf_hi(wa.x);
        a1 += hv.z * bf_lo(wa.y) + hv.w * bf_hi(wa.y);
        b0 += hv.x * bf_lo(wb.x) + hv.y * bf_hi(wb.x);
        b1v += hv.z * bf_lo(wb.y) + hv.w * bf_hi(wb.y);
      }
      pt3[s4][va] = a0 + a1;
      __syncthreads();
      float koa = 0.f;
      if (tid < 64) koa = pt3[0][tid] + pt3[1][tid] + pt3[2][tid] + pt3[3][tid];
      __syncthreads();
      pt3[s4][va] = b0 + b1v;
      __syncthreads();
      if (tid < 64)
        kout[tid] = b3r + koa;
      else if (tid < LD)
        kout[tid] = b3r + pt3[0][tid - 64] + pt3[1][tid - 64] + pt3[2][tid - 64] + pt3[3][tid - 64];
      __syncthreads();
    }
  };

  eval_f(times[0], vL, kb0, 0.f, kb0);   // k1 at t=0 (kb0 zero-initialized)

  for (int n = 0; n < NSTEP; n++) {
    float t0 = times[n * SPAN], t1 = times[(n + 1) * SPAN];
    float H = t1 - t0, tm = t0 + 0.5f * H;
    eval_f(tm, vL, kb0, 0.5f * H, kb1);   // k2
    eval_f(tm, vL, kb1, 0.5f * H, kb2);   // k3
    eval_f(t1, vL, kb2, H,        kb3);   // k4
    if (tid < LD)
      vNew[tid] = vL[tid] + (H / 6.0f) *
          (kb0[tid] + 2.f * kb1[tid] + 2.f * kb2[tid] + kb3[tid]);
    __syncthreads();
    eval_f(t1, vNew, kb0, 0.f, kb1);      // f at t1 (Hermite right slope)

    float invH = 1.0f / H;
    for (int idx = tid; idx < SPAN * LD; idx += 256) {
      int m_i = idx >> 7, k = idx & (LD - 1);
      int m = n * SPAN + 1 + m_i;
      float s  = (times[m] - t0) * invH;
      float s2 = s * s, s3 = s2 * s;
      float h00 = 2.f * s3 - 3.f * s2 + 1.f;
      float h10 = s3 - 2.f * s2 + s;
      float h01 = 3.f * s2 - 2.f * s3;
      float h11 = s3 - s2;
      float val = h00 * vL[k] + (h10 * H) * kb0[k]
                + h01 * vNew[k] + (h11 * H) * kb1[k];
      latent[((size_t)b * P_SZ + (m - 1)) * LD + k] = __float2bfloat16(val);
    }
    __syncthreads();
    if (tid < LD) { vL[tid] = vNew[tid]; kb0[tid] = kb1[tid]; }
    __syncthreads();
  }
}

// ---------------------------------------------------------------------------
// Kernel 2: zh[b][j] = bh[j] + sum_k z[b][128+k] * Wh[(129+k)][j]
// ---------------------------------------------------------------------------
__global__ __launch_bounds__(256) void zh_kernel(
    const float* __restrict__ z, const float* __restrict__ Wh,
    const float* __restrict__ bh, float* __restrict__ zh)
{
  const int b = blockIdx.x, j = threadIdx.x;
  __shared__ float zr[LD];
  if (j < LD) zr[j] = z[b * ZD + LD + j];
  __syncthreads();
  float acc = bh[j];
#pragma unroll 8
  for (int k = 0; k < LD; k += 4) {
    float4 zv = *(const float4*)&zr[k];
    acc += zv.x * Wh[(LD + 1 + k) * HD + j] + zv.y * Wh[(LD + 2 + k) * HD + j]
         + zv.z * Wh[(LD + 3 + k) * HD + j] + zv.w * Wh[(LD + 4 + k) * HD + j];
  }
  zh[b * HD + j] = acc;
}

// ---------------------------------------------------------------------------
// Kernel 3: decode. bf16-packed Wh rows 1..128; wave-local reductions.
// ---------------------------------------------------------------------------
__global__ __launch_bounds__(256) void decode_kernel(
    const float* __restrict__ x, const __hip_bfloat16* __restrict__ latent,
    const float* __restrict__ zh, const float* __restrict__ Wh,
    const uint2* __restrict__ Whq,
    const float* __restrict__ Wmu, const float* __restrict__ bmu,
    const float* __restrict__ Wsig, const float* __restrict__ bsig,
    float* __restrict__ out)
{
  const int b  = blockIdx.y;
  const int p0 = blockIdx.x * TT;
  const int j  = threadIdx.x;
  __shared__ float lat[TT][LD];
  __shared__ float hid[TT][HD];
  __shared__ float xv[TT];
  __shared__ float zhs[HD];

  // latent bf16 -> LDS fp32 (dword = 2 bf16)
  {
    const unsigned int* lp = (const unsigned int*)latent;
    for (int idx = j; idx < TT * LD / 2; idx += 256) {
      int t = idx >> 6, kk = (idx & 63) * 2;
      unsigned int ld2 = lp[((size_t)b * P_SZ + p0 + t) * (LD / 2) + (idx & 63)];
      lat[t][kk]     = __uint_as_float(ld2 << 16);
      lat[t][kk + 1] = __uint_as_float(ld2 & 0xffff0000u);
    }
  }
  if (j < TT) xv[j] = x[b * P_SZ + p0 + j];
  zhs[j] = zh[b * HD + j];
  __syncthreads();

  // phase 1: hidden[t][j] = relu(x*Wh0 + latent@Wh[1:129] + zh)
  float acc[TT];
  float wh0 = Wh[j];
  float zhj = zhs[j];
#pragma unroll
  for (int t = 0; t < TT; t++) acc[t] = zhj + xv[t] * wh0;

  for (int k = 0; k < LD; k += 4) {
    uint2 w = Whq[(k >> 2) * HD + j];
    float w0 = bf_lo(w.x), w1 = bf_hi(w.x), w2 = bf_lo(w.y), w3 = bf_hi(w.y);
#pragma unroll
    for (int t = 0; t < TT; t++) {
      float4 lv = *(const float4*)&lat[t][k];
      acc[t] += lv.x * w0 + lv.y * w1 + lv.z * w2 + lv.w * w3;
    }
  }
#pragma unroll
  for (int t = 0; t < TT; t++) hid[t][j] = fmaxf(acc[t], 0.f);
  __syncthreads();

  // phase 2: each wave handles 4 points; lanewise partial over 384-dim, shfl reduce
  const int w = j >> 6, l = j & 63;
  float wmu_h[4], wsg_h[4], wmu_l[2], wsg_l[2];
#pragma unroll
  for (int c = 0; c < 4; c++) {
    wmu_h[c] = Wmu[LD + l + 64 * c];
    wsg_h[c] = Wsig[LD + l + 64 * c];
  }
#pragma unroll
  for (int c = 0; c < 2; c++) {
    wmu_l[c] = Wmu[l + 64 * c];
    wsg_l[c] = Wsig[l + 64 * c];
  }
  const float bmu0 = bmu[0], bsg0 = bsig[0];

#pragma unroll
  for (int tt = 0; tt < 4; tt++) {
    int t = w * 4 + tt;
    float m = 0.f, sg = 0.f;
#pragma unroll
    for (int c = 0; c < 4; c++) {
      float hv = hid[t][l + 64 * c];
      m += hv * wmu_h[c]; sg += hv * wsg_h[c];
    }
#pragma unroll
    for (int c = 0; c < 2; c++) {
      float lv = lat[t][l + 64 * c];
      m += lv * wmu_l[c]; sg += lv * wsg_l[c];
    }
#pragma unroll
    for (int off = 32; off > 0; off >>= 1) {
      m  += __shfl_down(m, off);
      sg += __shfl_down(sg, off);
    }
    if (l == 0) {
      out[(size_t)b * P_SZ + p0 + t] = m + bmu0;
      float sv = sg + bsg0;
      float sp = (sv > 20.f) ? sv : log1pf(__expf(sv));
      out[(size_t)B_SZ * P_SZ + b * P_SZ + p0 + t] = 0.1f + 0.9f * sp;
    }
  }
}

// ---------------------------------------------------------------------------
extern "C" void kernel_launch(void* const* d_in, const int* in_sizes, int n_in,
                              void* d_out, int out_size, void* d_ws, size_t ws_size,
                              hipStream_t stream) {
  const float* x    = (const float*)d_in[0];
  const float* z    = (const float*)d_in[1];
  const float* x0   = (const float*)d_in[2];
  const float* W1   = (const float*)d_in[3];
  const float* b1   = (const float*)d_in[4];
  const float* W2   = (const float*)d_in[5];
  const float* b2   = (const float*)d_in[6];
  const float* W3   = (const float*)d_in[7];
  const float* b3   = (const float*)d_in[8];
  const float* Wh   = (const float*)d_in[9];
  const float* bh   = (const float*)d_in[10];
  const float* Wmu  = (const float*)d_in[11];
  const float* bmu  = (const float*)d_in[12];
  const float* Wsig = (const float*)d_in[13];
  const float* bsig = (const float*)d_in[14];
  float* out = (float*)d_out;

  char* ws = (char*)d_ws;
  __hip_bfloat16* latent = (__hip_bfloat16*)ws;                  // 16,777,216 B
  float* zh  = (float*)(ws + 16777216);                           //    262,144 B
  uint2* W1q = (uint2*)(ws + 17039360);                           //     65,536 B
  uint2* W2q = (uint2*)(ws + 17104896);                           //    131,072 B
  uint2* W3q = (uint2*)(ws + 17235968);                           //     65,536 B
  uint2* Whq = (uint2*)(ws + 17301504);                           //     65,536 B

  pack_kernel<<<dim3(160), dim3(256), 0, stream>>>(W1, W2, W3, Wh,
                                                   W1q, W2q, W3q, Whq);
  zh_kernel<<<dim3(B_SZ), dim3(256), 0, stream>>>(z, Wh, bh, zh);
  ode_kernel<<<dim3(B_SZ), dim3(256), 0, stream>>>(
      x, z, x0, W1, b1, b2, b3, W1q, W2q, W3q, latent);
  decode_kernel<<<dim3(P_SZ / TT, B_SZ), dim3(256), 0, stream>>>(
      x, latent, zh, Wh, Whq, Wmu, bmu, Wsig, bsig, out);
}

// Round 5
// 963.361 us; speedup vs baseline: 1.4290x; 1.4290x over previous
//
#include <hip/hip_runtime.h>
#include <hip/hip_bf16.h>
#include <math.h>

// Problem dims (fixed by reference)
#define B_SZ 256
#define P_SZ 256
#define LD   128   // L_DIM (evolving part)
#define ZD   256   // Z_DIM
#define HD   256   // H_DIM
#define NSTEP 8            // RK4 macro steps over [0,1]
#define SPAN (P_SZ/NSTEP)  // fine intervals per macro step = 32
#define TT   16            // points per block in decode kernel

__device__ __forceinline__ float fast_tanh(float v) {
  float e = __expf(2.0f * fabsf(v));
  float r = 1.0f - 2.0f / (e + 1.0f);
  return copysignf(r, v);
}

__device__ __forceinline__ unsigned int bf_bits(float f) {
  unsigned int u = __float_as_uint(f);
  return (u + 0x7fffu + ((u >> 16) & 1u)) >> 16;   // RNE
}
__device__ __forceinline__ float bf_lo(unsigned int u) {
  return __uint_as_float(u << 16);
}
__device__ __forceinline__ float bf_hi(unsigned int u) {
  return __uint_as_float(u & 0xffff0000u);
}
// opaque register pin: the value becomes an asm output, so the compiler
// cannot rematerialize the load that produced it — it must keep the regs.
__device__ __forceinline__ void pin(uint2& w) {
  asm volatile("" : "+v"(w.x), "+v"(w.y));
}

// ---------------------------------------------------------------------------
// Prep: pack W1[0:128], W2, W3, Wh[1:129] into bf16 k-pair uint2 layout.
// ---------------------------------------------------------------------------
__global__ __launch_bounds__(256) void pack_kernel(
    const float* __restrict__ W1, const float* __restrict__ W2,
    const float* __restrict__ W3, const float* __restrict__ Wh,
    uint2* __restrict__ W1q, uint2* __restrict__ W2q,
    uint2* __restrict__ W3q, uint2* __restrict__ Whq)
{
  int idx = blockIdx.x * 256 + threadIdx.x;
  if (idx < 8192) {
    int r = idx >> 8, u = idx & 255, k = r * 4;
    uint2 o;
    o.x = bf_bits(W1[(k + 0) * HD + u]) | (bf_bits(W1[(k + 1) * HD + u]) << 16);
    o.y = bf_bits(W1[(k + 2) * HD + u]) | (bf_bits(W1[(k + 3) * HD + u]) << 16);
    W1q[idx] = o;
  } else if (idx < 24576) {
    int i = idx - 8192;
    int r = i >> 8, u = i & 255, k = r * 4;
    uint2 o;
    o.x = bf_bits(W2[(k + 0) * HD + u]) | (bf_bits(W2[(k + 1) * HD + u]) << 16);
    o.y = bf_bits(W2[(k + 2) * HD + u]) | (bf_bits(W2[(k + 3) * HD + u]) << 16);
    W2q[i] = o;
  } else if (idx < 32768) {
    int i = idx - 24576;
    int r = i >> 7, u = i & 127, k = r * 4;
    uint2 o;
    o.x = bf_bits(W3[(k + 0) * LD + u]) | (bf_bits(W3[(k + 1) * LD + u]) << 16);
    o.y = bf_bits(W3[(k + 2) * LD + u]) | (bf_bits(W3[(k + 3) * LD + u]) << 16);
    W3q[i] = o;
  } else {
    int i = idx - 32768;
    int r = i >> 8, u = i & 255, k = r * 4;
    uint2 o;
    o.x = bf_bits(Wh[(1 + k) * HD + u]) | (bf_bits(Wh[(2 + k) * HD + u]) << 16);
    o.y = bf_bits(Wh[(3 + k) * HD + u]) | (bf_bits(Wh[(4 + k) * HD + u]) << 16);
    Whq[i] = o;
  }
}

// ---------------------------------------------------------------------------
// Kernel 1: one batch row per block, 512 threads, split-K 2 (layers 1/2) /
// split-K 4 (layer 3). Weights PINNED register-resident: 64 uint2 = 128
// VGPRs/thread; __launch_bounds__(512,2) keeps total under the 256 cap so
// nothing spills (R3 lesson) and the pin forbids remat (R2 lesson).
// RK4 + cubic-Hermite dense output -> latent (bf16).
// ---------------------------------------------------------------------------
__global__ __launch_bounds__(512, 2) void ode_kernel(
    const float* __restrict__ x, const float* __restrict__ z,
    const float* __restrict__ x0,
    const float* __restrict__ W1, const float* __restrict__ b1,
    const float* __restrict__ b2, const float* __restrict__ b3,
    const uint2* __restrict__ W1q, const uint2* __restrict__ W2q,
    const uint2* __restrict__ W3q,
    __hip_bfloat16* __restrict__ latent)
{
  __shared__ float times[P_SZ + 1];
  __shared__ float vL[LD], vNew[LD], vin[LD], zf[LD];
  __shared__ float kb0[LD], kb1[LD], kb2[LD], kb3[LD];
  __shared__ float c1[HD], h1s[HD], h2s[HD];
  __shared__ float part[4][HD];

  const int tid = threadIdx.x;
  const int b   = blockIdx.x;
  const int u8  = tid & 255;   // hidden-unit index (layers 1/2)
  const int h2i = tid >> 8;    // split-K half (layers 1/2)
  const int u7  = tid & 127;   // output index (layer 3)
  const int s4  = tid >> 7;    // split-K quarter (layer 3)

  // ---- load this thread's weight slice into registers ONCE, pin it ----
  uint2 rw1[16], rw2[32], rw3[16];
#pragma unroll
  for (int i = 0; i < 16; i++) rw1[i] = W1q[(h2i * 16 + i) * HD + u8];
#pragma unroll
  for (int i = 0; i < 32; i++) rw2[i] = W2q[(h2i * 32 + i) * HD + u8];
#pragma unroll
  for (int i = 0; i < 16; i++) rw3[i] = W3q[(s4 * 16 + i) * LD + u7];
#pragma unroll
  for (int i = 0; i < 16; i++) { pin(rw1[i]); pin(rw3[i]); }
#pragma unroll
  for (int i = 0; i < 32; i++) { pin(rw2[i]); }

  const float b2r = b2[u8];
  const float b3r = b3[u7];
  const float w1t = W1[ZD * HD + u8];   // W1 time row (fp32)

  for (int m = tid; m <= P_SZ; m += 512) times[m] = (m == 0) ? x0[0] : x[m - 1];
  if (tid < LD) {
    vL[tid] = z[b * ZD + tid];
    zf[tid] = z[b * ZD + LD + tid];
    kb0[tid] = 0.f;
  }
  __syncthreads();

  // c1[u] = b1[u] + zf . W1[128..255][u]  (fp32 weights, once per block)
  {
    float a0 = 0.f, a1 = 0.f, a2 = 0.f, a3 = 0.f;
    int kb = h2i * 64;
#pragma unroll 4
    for (int k = kb; k < kb + 64; k += 4) {
      float4 zv = *(const float4*)&zf[k];
      a0 += zv.x * W1[(LD + k + 0) * HD + u8];
      a1 += zv.y * W1[(LD + k + 1) * HD + u8];
      a2 += zv.z * W1[(LD + k + 2) * HD + u8];
      a3 += zv.w * W1[(LD + k + 3) * HD + u8];
    }
    part[h2i][u8] = (a0 + a1) + (a2 + a3);
    __syncthreads();
    if (tid < HD) c1[tid] = b1[tid] + part[0][tid] + part[1][tid];
    __syncthreads();
  }

  // kout = f_L(t, vsrc + c*kin)
  auto eval_f = [&](float t, float* vsrc, float* kin, float c, float* kout) {
    if (tid < LD) vin[tid] = vsrc[tid] + c * kin[tid];
    __syncthreads();
    // layer 1 (K = 64 per half from registers; zf+b1 folded into c1; + time)
    {
      float a0 = 0.f, a1 = 0.f, a2 = 0.f, a3 = 0.f;
#pragma unroll
      for (int i = 0; i < 16; i++) {
        float4 vv = *(const float4*)&vin[h2i * 64 + i * 4];
        uint2 w = rw1[i];
        a0 += vv.x * bf_lo(w.x); a1 += vv.y * bf_hi(w.x);
        a2 += vv.z * bf_lo(w.y); a3 += vv.w * bf_hi(w.y);
      }
      float acc = (a0 + a1) + (a2 + a3);
      acc += (h2i == 0) ? c1[u8] : t * w1t;
      part[h2i][u8] = acc;
    }
    __syncthreads();
    if (tid < HD) h1s[tid] = fast_tanh(part[0][tid] + part[1][tid]);
    __syncthreads();
    // layer 2 (K = 128 per half from registers)
    {
      float a0 = 0.f, a1 = 0.f, a2 = 0.f, a3 = 0.f;
#pragma unroll
      for (int i = 0; i < 32; i++) {
        float4 hv = *(const float4*)&h1s[h2i * 128 + i * 4];
        uint2 w = rw2[i];
        a0 += hv.x * bf_lo(w.x); a1 += hv.y * bf_hi(w.x);
        a2 += hv.z * bf_lo(w.y); a3 += hv.w * bf_hi(w.y);
      }
      part[h2i][u8] = (a0 + a1) + (a2 + a3);
    }
    __syncthreads();
    if (tid < HD) h2s[tid] = fast_tanh(part[0][tid] + part[1][tid] + b2r);
    __syncthreads();
    // layer 3 (K = 64 per quarter from registers)
    {
      float a0 = 0.f, a1 = 0.f, a2 = 0.f, a3 = 0.f;
#pragma unroll
      for (int i = 0; i < 16; i++) {
        float4 hv = *(const float4*)&h2s[s4 * 64 + i * 4];
        uint2 w = rw3[i];
        a0 += hv.x * bf_lo(w.x); a1 += hv.y * bf_hi(w.x);
        a2 += hv.z * bf_lo(w.y); a3 += hv.w * bf_hi(w.y);
      }
      part[s4][u7] = (a0 + a1) + (a2 + a3);
    }
    __syncthreads();
    if (tid < LD)
      kout[tid] = b3r + part[0][tid] + part[1][tid] + part[2][tid] + part[3][tid];
    __syncthreads();
  };

  eval_f(times[0], vL, kb0, 0.f, kb0);   // k1 at t=0 (kb0 zero-initialized)

  for (int n = 0; n < NSTEP; n++) {
    float t0 = times[n * SPAN], t1 = times[(n + 1) * SPAN];
    float H = t1 - t0, tm = t0 + 0.5f * H;
    eval_f(tm, vL, kb0, 0.5f * H, kb1);   // k2
    eval_f(tm, vL, kb1, 0.5f * H, kb2);   // k3
    eval_f(t1, vL, kb2, H,        kb3);   // k4
    if (tid < LD)
      vNew[tid] = vL[tid] + (H / 6.0f) *
          (kb0[tid] + 2.f * kb1[tid] + 2.f * kb2[tid] + kb3[tid]);
    __syncthreads();
    eval_f(t1, vNew, kb0, 0.f, kb1);      // f at t1 (Hermite right slope)

    float invH = 1.0f / H;
    for (int idx = tid; idx < SPAN * LD; idx += 512) {
      int m_i = idx >> 7, k = idx & (LD - 1);
      int m = n * SPAN + 1 + m_i;
      float s  = (times[m] - t0) * invH;
      float s2 = s * s, s3 = s2 * s;
      float h00 = 2.f * s3 - 3.f * s2 + 1.f;
      float h10 = s3 - 2.f * s2 + s;
      float h01 = 3.f * s2 - 2.f * s3;
      float h11 = s3 - s2;
      float val = h00 * vL[k] + (h10 * H) * kb0[k]
                + h01 * vNew[k] + (h11 * H) * kb1[k];
      latent[((size_t)b * P_SZ + (m - 1)) * LD + k] = __float2bfloat16(val);
    }
    __syncthreads();
    if (tid < LD) { vL[tid] = vNew[tid]; kb0[tid] = kb1[tid]; }
    __syncthreads();
  }
}

// ---------------------------------------------------------------------------
// Kernel 2: zh[b][j] = bh[j] + sum_k z[b][128+k] * Wh[(129+k)][j]
// ---------------------------------------------------------------------------
__global__ __launch_bounds__(256) void zh_kernel(
    const float* __restrict__ z, const float* __restrict__ Wh,
    const float* __restrict__ bh, float* __restrict__ zh)
{
  const int b = blockIdx.x, j = threadIdx.x;
  __shared__ float zr[LD];
  if (j < LD) zr[j] = z[b * ZD + LD + j];
  __syncthreads();
  float acc = bh[j];
#pragma unroll 8
  for (int k = 0; k < LD; k += 4) {
    float4 zv = *(const float4*)&zr[k];
    acc += zv.x * Wh[(LD + 1 + k) * HD + j] + zv.y * Wh[(LD + 2 + k) * HD + j]
         + zv.z * Wh[(LD + 3 + k) * HD + j] + zv.w * Wh[(LD + 4 + k) * HD + j];
  }
  zh[b * HD + j] = acc;
}

// ---------------------------------------------------------------------------
// Kernel 3: decode. bf16-packed Wh rows 1..128; wave-local reductions.
// ---------------------------------------------------------------------------
__global__ __launch_bounds__(256) void decode_kernel(
    const float* __restrict__ x, const __hip_bfloat16* __restrict__ latent,
    const float* __restrict__ zh, const float* __restrict__ Wh,
    const uint2* __restrict__ Whq,
    const float* __restrict__ Wmu, const float* __restrict__ bmu,
    const float* __restrict__ Wsig, const float* __restrict__ bsig,
    float* __restrict__ out)
{
  const int b  = blockIdx.y;
  const int p0 = blockIdx.x * TT;
  const int j  = threadIdx.x;
  __shared__ float lat[TT][LD];
  __shared__ float hid[TT][HD];
  __shared__ float xv[TT];
  __shared__ float zhs[HD];

  // latent bf16 -> LDS fp32 (dword = 2 bf16)
  {
    const unsigned int* lp = (const unsigned int*)latent;
    for (int idx = j; idx < TT * LD / 2; idx += 256) {
      int t = idx >> 6, kk = (idx & 63) * 2;
      unsigned int ld2 = lp[((size_t)b * P_SZ + p0 + t) * (LD / 2) + (idx & 63)];
      lat[t][kk]     = __uint_as_float(ld2 << 16);
      lat[t][kk + 1] = __uint_as_float(ld2 & 0xffff0000u);
    }
  }
  if (j < TT) xv[j] = x[b * P_SZ + p0 + j];
  zhs[j] = zh[b * HD + j];
  __syncthreads();

  // phase 1: hidden[t][j] = relu(x*Wh0 + latent@Wh[1:129] + zh)
  float acc[TT];
  float wh0 = Wh[j];
  float zhj = zhs[j];
#pragma unroll
  for (int t = 0; t < TT; t++) acc[t] = zhj + xv[t] * wh0;

  for (int k = 0; k < LD; k += 4) {
    uint2 w = Whq[(k >> 2) * HD + j];
    float w0 = bf_lo(w.x), w1 = bf_hi(w.x), w2 = bf_lo(w.y), w3 = bf_hi(w.y);
#pragma unroll
    for (int t = 0; t < TT; t++) {
      float4 lv = *(const float4*)&lat[t][k];
      acc[t] += lv.x * w0 + lv.y * w1 + lv.z * w2 + lv.w * w3;
    }
  }
#pragma unroll
  for (int t = 0; t < TT; t++) hid[t][j] = fmaxf(acc[t], 0.f);
  __syncthreads();

  // phase 2: each wave handles 4 points; lanewise partial over 384-dim, shfl reduce
  const int w = j >> 6, l = j & 63;
  float wmu_h[4], wsg_h[4], wmu_l[2], wsg_l[2];
#pragma unroll
  for (int c = 0; c < 4; c++) {
    wmu_h[c] = Wmu[LD + l + 64 * c];
    wsg_h[c] = Wsig[LD + l + 64 * c];
  }
#pragma unroll
  for (int c = 0; c < 2; c++) {
    wmu_l[c] = Wmu[l + 64 * c];
    wsg_l[c] = Wsig[l + 64 * c];
  }
  const float bmu0 = bmu[0], bsg0 = bsig[0];

#pragma unroll
  for (int tt = 0; tt < 4; tt++) {
    int t = w * 4 + tt;
    float m = 0.f, sg = 0.f;
#pragma unroll
    for (int c = 0; c < 4; c++) {
      float hv = hid[t][l + 64 * c];
      m += hv * wmu_h[c]; sg += hv * wsg_h[c];
    }
#pragma unroll
    for (int c = 0; c < 2; c++) {
      float lv = lat[t][l + 64 * c];
      m += lv * wmu_l[c]; sg += lv * wsg_l[c];
    }
#pragma unroll
    for (int off = 32; off > 0; off >>= 1) {
      m  += __shfl_down(m, off);
      sg += __shfl_down(sg, off);
    }
    if (l == 0) {
      out[(size_t)b * P_SZ + p0 + t] = m + bmu0;
      float sv = sg + bsg0;
      float sp = (sv > 20.f) ? sv : log1pf(__expf(sv));
      out[(size_t)B_SZ * P_SZ + b * P_SZ + p0 + t] = 0.1f + 0.9f * sp;
    }
  }
}

// ---------------------------------------------------------------------------
extern "C" void kernel_launch(void* const* d_in, const int* in_sizes, int n_in,
                              void* d_out, int out_size, void* d_ws, size_t ws_size,
                              hipStream_t stream) {
  const float* x    = (const float*)d_in[0];
  const float* z    = (const float*)d_in[1];
  const float* x0   = (const float*)d_in[2];
  const float* W1   = (const float*)d_in[3];
  const float* b1   = (const float*)d_in[4];
  const float* W2   = (const float*)d_in[5];
  const float* b2   = (const float*)d_in[6];
  const float* W3   = (const float*)d_in[7];
  const float* b3   = (const float*)d_in[8];
  const float* Wh   = (const float*)d_in[9];
  const float* bh   = (const float*)d_in[10];
  const float* Wmu  = (const float*)d_in[11];
  const float* bmu  = (const float*)d_in[12];
  const float* Wsig = (const float*)d_in[13];
  const float* bsig = (const float*)d_in[14];
  float* out = (float*)d_out;

  char* ws = (char*)d_ws;
  __hip_bfloat16* latent = (__hip_bfloat16*)ws;                  // 16,777,216 B
  float* zh  = (float*)(ws + 16777216);                           //    262,144 B
  uint2* W1q = (uint2*)(ws + 17039360);                           //     65,536 B
  uint2* W2q = (uint2*)(ws + 17104896);                           //    131,072 B
  uint2* W3q = (uint2*)(ws + 17235968);                           //     65,536 B
  uint2* Whq = (uint2*)(ws + 17301504);                           //     65,536 B

  pack_kernel<<<dim3(160), dim3(256), 0, stream>>>(W1, W2, W3, Wh,
                                                   W1q, W2q, W3q, Whq);
  zh_kernel<<<dim3(B_SZ), dim3(256), 0, stream>>>(z, Wh, bh, zh);
  ode_kernel<<<dim3(B_SZ), dim3(512), 0, stream>>>(
      x, z, x0, W1, b1, b2, b3, W1q, W2q, W3q, latent);
  decode_kernel<<<dim3(P_SZ / TT, B_SZ), dim3(256), 0, stream>>>(
      x, latent, zh, Wh, Whq, Wmu, bmu, Wsig, bsig, out);
}